// Round 4
// baseline (247.138 us; speedup 1.0000x reference)
//
#include <hip/hip_runtime.h>
#include <math.h>

// Problem constants (B,K,N,M) = (32,128,128,256)
#define Bb 32
#define Kk 128
#define Nn 128
#define Mm 256
#define EPS2 0.01f      // EPSILON^2
#define LAMBDA_S 0.1f
#define LR 0.01f
#define BN_EPS_C 1e-5f

// ---------------------------------------------------------------------------
// kA: fused BatchNorm (blocks 0..127, one per channel n) + Psum=sum_k P[k]
// (blocks 128..191). grid 192, block 256.
__global__ void kA_bn_psum(const float* __restrict__ x, const float* __restrict__ P,
                           float* __restrict__ xn, float* __restrict__ Psum) {
  int t = threadIdx.x;
  if (blockIdx.x < 128) {
    int n = blockIdx.x;
    float s = 0.f, s2 = 0.f;
    #pragma unroll 4
    for (int b = 0; b < Bb; ++b) {
      float v = x[(size_t)b * (Nn * Mm) + n * Mm + t];
      s += v;
      s2 += v * v;
    }
    #pragma unroll
    for (int o = 32; o > 0; o >>= 1) {
      s += __shfl_down(s, o, 64);
      s2 += __shfl_down(s2, o, 64);
    }
    __shared__ float rs[4], rs2[4];
    if ((t & 63) == 0) { rs[t >> 6] = s; rs2[t >> 6] = s2; }
    __syncthreads();
    float S = rs[0] + rs[1] + rs[2] + rs[3];
    float S2 = rs2[0] + rs2[1] + rs2[2] + rs2[3];
    float mean = S * (1.0f / (Bb * Mm));
    float var = S2 * (1.0f / (Bb * Mm)) - mean * mean;
    float rstd = 1.0f / sqrtf(var + BN_EPS_C);
    #pragma unroll 4
    for (int b = 0; b < Bb; ++b) {
      size_t idx = (size_t)b * (Nn * Mm) + n * Mm + t;
      xn[idx] = (x[idx] - mean) * rstd;
    }
  } else {
    int e = (blockIdx.x - 128) * 256 + t;
    float s = 0.f;
    #pragma unroll 8
    for (int k = 0; k < Kk; ++k) s += P[(size_t)k * 16384 + e];
    Psum[e] = s;
  }
}

// ---------------------------------------------------------------------------
// K3: blocked Gauss-Jordan inverse (nb=16), register-resident 8x8 tiles.
// alpha computed inline from cnt (k0 eliminated). grid 129, block 256.
#define SWZ(c) (((c) & 14) | (((c) & 1) << 4) | (((c) >> 4) & 1))

__global__ __launch_bounds__(256, 1) void k3_invert(
    const float* __restrict__ P, const float* __restrict__ Psum,
    const float* __restrict__ cnt, float* __restrict__ C) {
  __shared__ float Mt[16 * 132];   // M transposed: Mt[q*132 + row], 8.4 KB
  __shared__ float Rb[16 * 128];   // R rows, float4-quad bit0<->bit4 swizzle, 8 KB
  __shared__ float redc[4];
  int blk = blockIdx.x;
  int t = threadIdx.x;
  int tx = t & 15, ty = t >> 4;

  // inline alpha: total = sum(cnt), then per-block alpha
  float cv = cnt[t & 127];
  float sr = cv;
  #pragma unroll
  for (int o = 32; o > 0; o >>= 1) sr += __shfl_down(sr, o, 64);
  if ((t & 63) == 0) redc[t >> 6] = sr;
  __syncthreads();
  float total = redc[0] + redc[1];  // waves 0,1 cover cnt[0..127]
  bool has = total > 1e-6f;
  float av;
  if (blk < 128) {
    float c = cnt[blk];
    float bk = (c != 0.0f) ? 1.0f : 0.0f;
    float cfix = c + (1.0f - bk);
    av = (float)Nn / (cfix * EPS2) * bk;
  } else {
    av = has ? ((float)Nn / (EPS2 * total)) : 0.0f;
  }
  const float* src = (blk < 128) ? (P + (size_t)blk * 16384) : Psum;

  // init a = av*src + I
  float a[8][8];
  #pragma unroll
  for (int i = 0; i < 8; ++i) {
    int row = ty * 8 + i;
    float4 p0 = *(const float4*)&src[row * 128 + tx * 8];
    float4 p1 = *(const float4*)&src[row * 128 + tx * 8 + 4];
    a[i][0] = av * p0.x; a[i][1] = av * p0.y; a[i][2] = av * p0.z; a[i][3] = av * p0.w;
    a[i][4] = av * p1.x; a[i][5] = av * p1.y; a[i][6] = av * p1.z; a[i][7] = av * p1.w;
    if (tx == ty) a[i][i] += 1.0f;
  }

  for (int kb = 0; kb < 8; ++kb) {
    int k0 = kb * 16;
    // --- Phase A: dumps ---
    if ((ty >> 1) == kb) {          // R: pre-panel pivot rows (full 128 cols)
      int d = ty & 1;
      #pragma unroll
      for (int i = 0; i < 8; ++i) {
        *(float4*)&Rb[(d * 8 + i) * 128 + SWZ(2 * tx) * 4] =
            make_float4(a[i][0], a[i][1], a[i][2], a[i][3]);
        *(float4*)&Rb[(d * 8 + i) * 128 + SWZ(2 * tx + 1) * 4] =
            make_float4(a[i][4], a[i][5], a[i][6], a[i][7]);
      }
    }
    if ((tx >> 1) == kb) {          // M pre-panel values, transposed
      int dh = tx & 1;
      #pragma unroll
      for (int i = 0; i < 8; ++i)
        #pragma unroll
        for (int j = 0; j < 8; ++j)
          Mt[(dh * 8 + j) * 132 + ty * 8 + i] = a[i][j];
    }
    __syncthreads();

    // --- Phase B: wave 0 factors the 128x16 panel (no barriers inside) ---
    if (t < 64) {
      int l = t;
      float m[2][16];
      #pragma unroll
      for (int d = 0; d < 2; ++d)
        #pragma unroll
        for (int j = 0; j < 16; ++j)
          m[d][j] = Mt[j * 132 + 2 * l + d];
      #pragma unroll
      for (int q = 0; q < 16; ++q) {
        int lq = (k0 + q) >> 1;           // uniform source lane
        float pr[16];
        #pragma unroll
        for (int j = 0; j < 16; ++j) pr[j] = __shfl(m[q & 1][j], lq, 64);
        float pinv = 1.0f / pr[q];
        #pragma unroll
        for (int d = 0; d < 2; ++d) {
          float f = m[d][q];
          bool isp = (2 * l + d == k0 + q);
          float g = isp ? (1.0f - pinv) : f * pinv;
          #pragma unroll
          for (int j = 0; j < 16; ++j) m[d][j] = fmaf(-g, pr[j], m[d][j]);
          m[d][q] = isp ? pinv : -g;
        }
      }
      #pragma unroll
      for (int d = 0; d < 2; ++d)
        #pragma unroll
        for (int j = 0; j < 16; ++j)
          Mt[j * 132 + 2 * l + d] = m[d][j];
    }
    __syncthreads();

    // --- Phase C: rank-16 trailing update ---
    if ((ty >> 1) == kb) {          // panel rows: old value dropped
      #pragma unroll
      for (int i = 0; i < 8; ++i)
        #pragma unroll
        for (int j = 0; j < 8; ++j) a[i][j] = 0.0f;
    }
    #pragma unroll
    for (int q = 0; q < 16; ++q) {
      float4 m0 = *(const float4*)&Mt[q * 132 + ty * 8];
      float4 m1 = *(const float4*)&Mt[q * 132 + ty * 8 + 4];
      float4 r0 = *(const float4*)&Rb[q * 128 + SWZ(2 * tx) * 4];
      float4 r1 = *(const float4*)&Rb[q * 128 + SWZ(2 * tx + 1) * 4];
      float mq[8] = {m0.x, m0.y, m0.z, m0.w, m1.x, m1.y, m1.z, m1.w};
      float rq[8] = {r0.x, r0.y, r0.z, r0.w, r1.x, r1.y, r1.z, r1.w};
      #pragma unroll
      for (int i = 0; i < 8; ++i)
        #pragma unroll
        for (int j = 0; j < 8; ++j)
          a[i][j] = fmaf(mq[i], rq[j], a[i][j]);
    }
    if ((tx >> 1) == kb) {          // panel cols: value IS M (reload)
      int dh = tx & 1;
      #pragma unroll
      for (int j = 0; j < 8; ++j) {
        float4 v0 = *(const float4*)&Mt[(dh * 8 + j) * 132 + ty * 8];
        float4 v1 = *(const float4*)&Mt[(dh * 8 + j) * 132 + ty * 8 + 4];
        a[0][j] = v0.x; a[1][j] = v0.y; a[2][j] = v0.z; a[3][j] = v0.w;
        a[4][j] = v1.x; a[5][j] = v1.y; a[6][j] = v1.z; a[7][j] = v1.w;
      }
    }
    __syncthreads();                // protect Mt/Rb before next panel's dumps
  }

  // scale by alpha and store
  float* dst = C + (size_t)blk * 16384;
  #pragma unroll
  for (int i = 0; i < 8; ++i) {
    int row = ty * 8 + i;
    float4 v0 = make_float4(av * a[i][0], av * a[i][1], av * a[i][2], av * a[i][3]);
    float4 v1 = make_float4(av * a[i][4], av * a[i][5], av * a[i][6], av * a[i][7]);
    *(float4*)&dst[row * 128 + tx * 8] = v0;
    *(float4*)&dst[row * 128 + tx * 8 + 4] = v1;
  }
}

// ---------------------------------------------------------------------------
// K45: fused Gram + S, global-direct (no LDS; operands live in L1/L2).
// blocks 0..511:  G_k = c_k * c_k^T (c symmetric => == c^T c).
//                 block = (k = bx>>2, tile y = bx&3): 64x64 tile, 4x4/thread.
// blocks 512..639: S_b = xn_b xn_b^T. block = (b = (bx-512)>>2, tile y&3).
// grid 640, block 256.
__global__ __launch_bounds__(256, 2) void k45_gram_S(
    const float* __restrict__ C, const float* __restrict__ xn,
    float* __restrict__ G, float* __restrict__ S) {
  int bx = blockIdx.x;
  int t = threadIdx.x;
  int tx = t & 15, ty = t >> 4;
  if (bx < 512) {
    int k = bx >> 2, y = bx & 3;
    int i0 = (y & 1) * 64 + ty * 4, j0 = (y >> 1) * 64 + tx * 4;
    const float* c = C + (size_t)k * 16384;
    float acc[4][4] = {};
    for (int l = 0; l < 128; l += 4) {
      float4 ar[4], br[4];
      #pragma unroll
      for (int q = 0; q < 4; ++q) ar[q] = *(const float4*)&c[(i0 + q) * 128 + l];
      #pragma unroll
      for (int q = 0; q < 4; ++q) br[q] = *(const float4*)&c[(j0 + q) * 128 + l];
      #pragma unroll
      for (int qi = 0; qi < 4; ++qi)
        #pragma unroll
        for (int qj = 0; qj < 4; ++qj) {
          acc[qi][qj] = fmaf(ar[qi].x, br[qj].x, acc[qi][qj]);
          acc[qi][qj] = fmaf(ar[qi].y, br[qj].y, acc[qi][qj]);
          acc[qi][qj] = fmaf(ar[qi].z, br[qj].z, acc[qi][qj]);
          acc[qi][qj] = fmaf(ar[qi].w, br[qj].w, acc[qi][qj]);
        }
    }
    float* dst = G + (size_t)k * 16384;
    #pragma unroll
    for (int qi = 0; qi < 4; ++qi)
      *(float4*)&dst[(i0 + qi) * 128 + j0] =
          make_float4(acc[qi][0], acc[qi][1], acc[qi][2], acc[qi][3]);
  } else {
    int bxx = bx - 512;
    int b = bxx >> 2, y = bxx & 3;
    int i0 = (y & 1) * 64 + ty * 4, j0 = (y >> 1) * 64 + tx * 4;
    const float* xb = xn + (size_t)b * (Nn * Mm);
    float acc[4][4] = {};
    for (int m = 0; m < Mm; m += 4) {
      float4 ar[4], br[4];
      #pragma unroll
      for (int q = 0; q < 4; ++q) ar[q] = *(const float4*)&xb[(i0 + q) * Mm + m];
      #pragma unroll
      for (int q = 0; q < 4; ++q) br[q] = *(const float4*)&xb[(j0 + q) * Mm + m];
      #pragma unroll
      for (int qi = 0; qi < 4; ++qi)
        #pragma unroll
        for (int qj = 0; qj < 4; ++qj) {
          acc[qi][qj] = fmaf(ar[qi].x, br[qj].x, acc[qi][qj]);
          acc[qi][qj] = fmaf(ar[qi].y, br[qj].y, acc[qi][qj]);
          acc[qi][qj] = fmaf(ar[qi].z, br[qj].z, acc[qi][qj]);
          acc[qi][qj] = fmaf(ar[qi].w, br[qj].w, acc[qi][qj]);
        }
    }
    float* dst = S + (size_t)b * 16384;
    #pragma unroll
    for (int qi = 0; qi < 4; ++qi)
      *(float4*)&dst[(i0 + qi) * 128 + j0] =
          make_float4(acc[qi][0], acc[qi][1], acc[qi][2], acc[qi][3]);
  }
}

// ---------------------------------------------------------------------------
// K6: partial[c][b][k] = sum over inner chunk c (64 of 16384) of G[k][.]*S[b][.].
// grid 256, block 256.
__global__ __launch_bounds__(256, 1) void k6_partial(const float* __restrict__ G,
                                                     const float* __restrict__ S,
                                                     float* __restrict__ part) {
  int c = blockIdx.x;
  int t = threadIdx.x;
  __shared__ float Gp[128 * 65];  // 33.3 KB
  __shared__ float Sp[32 * 65];   // 8.3 KB
  int off = c * 64;
  for (int q = 0; q < 32; ++q) {
    int e = q * 256 + t;
    int k = e >> 6, jj = e & 63;
    Gp[k * 65 + jj] = G[(size_t)k * 16384 + off + jj];
  }
  for (int q = 0; q < 8; ++q) {
    int e = q * 256 + t;
    int b = e >> 6, jj = e & 63;
    Sp[b * 65 + jj] = S[(size_t)b * 16384 + off + jj];
  }
  __syncthreads();
  int tk = t & 15, tb = t >> 4;  // k = tk + 16q (bank-friendly), b = tb*2 + bb
  float acc[2][8] = {};
  for (int jj = 0; jj < 64; ++jj) {
    float sv0 = Sp[(tb * 2) * 65 + jj];
    float sv1 = Sp[(tb * 2 + 1) * 65 + jj];
    float gv[8];
    #pragma unroll
    for (int q = 0; q < 8; ++q) gv[q] = Gp[(tk + 16 * q) * 65 + jj];
    #pragma unroll
    for (int q = 0; q < 8; ++q) {
      acc[0][q] = fmaf(sv0, gv[q], acc[0][q]);
      acc[1][q] = fmaf(sv1, gv[q], acc[1][q]);
    }
  }
  float* pout = part + (size_t)c * 4096;
  #pragma unroll
  for (int bb = 0; bb < 2; ++bb)
    #pragma unroll
    for (int q = 0; q < 8; ++q)
      pout[(tb * 2 + bb) * 128 + tk + 16 * q] = acc[bb][q];
}

// ---------------------------------------------------------------------------
// K7: reduce partials -> norm -> rescale to sum 10 -> softmax -> w[k][b]=gama*pi.
// gama/total computed inline from cnt. grid 32 (one per b), block 256.
__global__ void k7_weights(const float* __restrict__ part,
                           const float* __restrict__ cnt, float* __restrict__ wT) {
  int b = blockIdx.x;
  int t = threadIdx.x;
  int k = t & 127, h = t >> 7;
  float s = 0.f;
  #pragma unroll 8
  for (int c = h * 128; c < h * 128 + 128; ++c)
    s += part[(size_t)c * 4096 + b * 128 + k];
  __shared__ float sh[256];
  sh[t] = s;
  __syncthreads();
  float norm2 = sh[k] + sh[k + 128];  // both halves compute identical values
  float norm = sqrtf(fmaxf(norm2, 0.0f));
  float cv = cnt[k];
  // total over k (waves 0,1 cover k=0..127)
  float tt = cv;
  #pragma unroll
  for (int o = 32; o > 0; o >>= 1) tt += __shfl_down(tt, o, 64);
  __shared__ float redt[4];
  if ((t & 63) == 0) redt[t >> 6] = tt;
  // sum of norms over 256 threads = 2 * (sum over k)
  float r = norm;
  #pragma unroll
  for (int o = 32; o > 0; o >>= 1) r += __shfl_down(r, o, 64);
  __shared__ float red[4];
  if ((t & 63) == 0) red[t >> 6] = r;
  __syncthreads();
  float total = redt[0] + redt[1];
  float sumn = 0.5f * (red[0] + red[1] + red[2] + red[3]);
  float nr = 10.0f * norm / fmaxf(sumn, 1e-30f);
  float ex = expf(-LAMBDA_S * nr);
  float r2 = ex;
  #pragma unroll
  for (int o = 32; o > 0; o >>= 1) r2 += __shfl_down(r2, o, 64);
  __shared__ float red2[4];
  if ((t & 63) == 0) red2[t >> 6] = r2;
  __syncthreads();
  float sume = 0.5f * (red2[0] + red2[1] + red2[2] + red2[3]);
  float bk = (cv != 0.0f) ? 1.0f : 0.0f;
  float pi = (ex / sume) * bk;
  float gama = (total > 1e-6f) ? (cv / total) : 0.0f;
  if (h == 0) wT[k * 32 + b] = gama * pi;  // transposed for K8 scalar loads
}

// ---------------------------------------------------------------------------
// K8: F[b] = e - sum_k w[b][k] * c_k. grid (64,4), block 256; each thread
// one (i,j) element x 8 b-accumulators.
__global__ __launch_bounds__(256, 1) void k8_F(const float* __restrict__ C,
                                               const float* __restrict__ E,
                                               const float* __restrict__ wT,
                                               float* __restrict__ F) {
  int e = blockIdx.x * 256 + threadIdx.x;
  int b0 = blockIdx.y * 8;
  float acc[8];
  float ev = E[e];
  #pragma unroll
  for (int b = 0; b < 8; ++b) acc[b] = ev;
  for (int k = 0; k < 128; ++k) {
    float cv = C[(size_t)k * 16384 + e];
    const float* wk = wT + k * 32 + b0;  // uniform -> s_load
    #pragma unroll
    for (int b = 0; b < 8; ++b) acc[b] = fmaf(-wk[b], cv, acc[b]);
  }
  #pragma unroll
  for (int b = 0; b < 8; ++b) F[(size_t)(b0 + b) * 16384 + e] = acc[b];
}

// ---------------------------------------------------------------------------
// K9 v2: out[b] = xn[b] + LR * F[b] @ xn[b], global-direct (no LDS).
// grid (32,8): i-half = y&1, m-quarter = y>>1. 4x4 outputs per thread.
__global__ __launch_bounds__(256, 2) void k9_out(const float* __restrict__ F,
                                                 const float* __restrict__ xn,
                                                 float* __restrict__ out) {
  int b = blockIdx.x;
  int y = blockIdx.y;
  int t = threadIdx.x;
  int tx = t & 15, ty = t >> 4;
  int i0 = (y & 1) * 64 + ty * 4;
  int m0 = (y >> 1) * 64 + tx * 4;
  const float* Fb = F + (size_t)b * 16384;
  const float* xb = xn + (size_t)b * (Nn * Mm);
  float acc[4][4] = {};
  for (int j = 0; j < 128; j += 4) {
    float4 fr[4], xr[4];
    #pragma unroll
    for (int q = 0; q < 4; ++q) fr[q] = *(const float4*)&Fb[(i0 + q) * 128 + j];
    #pragma unroll
    for (int q = 0; q < 4; ++q) xr[q] = *(const float4*)&xb[(j + q) * Mm + m0];
    #pragma unroll
    for (int qi = 0; qi < 4; ++qi) {
      #pragma unroll
      for (int qm = 0; qm < 4; ++qm) {
        float xv0 = ((const float*)&xr[0])[qm];
        float xv1 = ((const float*)&xr[1])[qm];
        float xv2 = ((const float*)&xr[2])[qm];
        float xv3 = ((const float*)&xr[3])[qm];
        acc[qi][qm] = fmaf(fr[qi].x, xv0, acc[qi][qm]);
        acc[qi][qm] = fmaf(fr[qi].y, xv1, acc[qi][qm]);
        acc[qi][qm] = fmaf(fr[qi].z, xv2, acc[qi][qm]);
        acc[qi][qm] = fmaf(fr[qi].w, xv3, acc[qi][qm]);
      }
    }
  }
  #pragma unroll
  for (int qi = 0; qi < 4; ++qi) {
    float4 xv = *(const float4*)&xb[(i0 + qi) * Mm + m0];
    float4 o;
    o.x = fmaf(LR, acc[qi][0], xv.x);
    o.y = fmaf(LR, acc[qi][1], xv.y);
    o.z = fmaf(LR, acc[qi][2], xv.z);
    o.w = fmaf(LR, acc[qi][3], xv.w);
    *(float4*)&out[(size_t)b * (Nn * Mm) + (i0 + qi) * Mm + m0] = o;
  }
}

// ---------------------------------------------------------------------------
extern "C" void kernel_launch(void* const* d_in, const int* in_sizes, int n_in,
                              void* d_out, int out_size, void* d_ws, size_t ws_size,
                              hipStream_t stream) {
  const float* x = (const float*)d_in[0];     // (32,128,256)
  const float* P = (const float*)d_in[1];     // (128,128,128) EC_proto
  const float* cnt = (const float*)d_in[2];   // (128,)
  float* out = (float*)d_out;

  float* ws = (float*)d_ws;
  float* xn = ws;                               // 1048576
  float* C = xn + 1048576;                      // 129*16384 (c_k; slot 128 = e)
  float* G = C + 2113536;                       // 2097152
  float* S = G + 2097152;                       // 524288
  float* part = S + 524288;                     // 1048576
  float* F = part + 1048576;                    // 524288
  float* wT = F + 524288;                       // 4096
  float* Psum = wT + 4096;                      // 16384
  size_t need_bytes = (size_t)((Psum + 16384) - ws) * sizeof(float);
  if (ws_size < need_bytes) return;  // ~29.5 MB required

  hipLaunchKernelGGL(kA_bn_psum, dim3(192), dim3(256), 0, stream, x, P, xn, Psum);
  hipLaunchKernelGGL(k3_invert, dim3(129), dim3(256), 0, stream, P, Psum, cnt, C);
  hipLaunchKernelGGL(k45_gram_S, dim3(640), dim3(256), 0, stream, C, xn, G, S);
  hipLaunchKernelGGL(k6_partial, dim3(256), dim3(256), 0, stream, G, S, part);
  hipLaunchKernelGGL(k7_weights, dim3(32), dim3(256), 0, stream, part, cnt, wT);
  hipLaunchKernelGGL(k8_F, dim3(64, 4), dim3(256), 0, stream, C, C + (size_t)128 * 16384, wT, F);
  hipLaunchKernelGGL(k9_out, dim3(32, 8), dim3(256), 0, stream, F, xn, out);
}

// Round 5
// 199.717 us; speedup vs baseline: 1.2374x; 1.2374x over previous
//
#include <hip/hip_runtime.h>
#include <math.h>

// Problem constants (B,K,N,M) = (32,128,128,256)
#define Bb 32
#define Kk 128
#define Nn 128
#define Mm 256
#define EPS2 0.01f      // EPSILON^2
#define LAMBDA_S 0.1f
#define LR 0.01f
#define BN_EPS_C 1e-5f

// ---------------------------------------------------------------------------
// kA: fused BatchNorm (blocks 0..127, one per channel n) + Psum=sum_k P[k]
// (blocks 128..191). grid 192, block 256.
__global__ void kA_bn_psum(const float* __restrict__ x, const float* __restrict__ P,
                           float* __restrict__ xn, float* __restrict__ Psum) {
  int t = threadIdx.x;
  if (blockIdx.x < 128) {
    int n = blockIdx.x;
    float s = 0.f, s2 = 0.f;
    #pragma unroll 4
    for (int b = 0; b < Bb; ++b) {
      float v = x[(size_t)b * (Nn * Mm) + n * Mm + t];
      s += v;
      s2 += v * v;
    }
    #pragma unroll
    for (int o = 32; o > 0; o >>= 1) {
      s += __shfl_down(s, o, 64);
      s2 += __shfl_down(s2, o, 64);
    }
    __shared__ float rs[4], rs2[4];
    if ((t & 63) == 0) { rs[t >> 6] = s; rs2[t >> 6] = s2; }
    __syncthreads();
    float S = rs[0] + rs[1] + rs[2] + rs[3];
    float S2 = rs2[0] + rs2[1] + rs2[2] + rs2[3];
    float mean = S * (1.0f / (Bb * Mm));
    float var = S2 * (1.0f / (Bb * Mm)) - mean * mean;
    float rstd = 1.0f / sqrtf(var + BN_EPS_C);
    #pragma unroll 4
    for (int b = 0; b < Bb; ++b) {
      size_t idx = (size_t)b * (Nn * Mm) + n * Mm + t;
      xn[idx] = (x[idx] - mean) * rstd;
    }
  } else {
    int e = (blockIdx.x - 128) * 256 + t;
    float s = 0.f;
    #pragma unroll 8
    for (int k = 0; k < Kk; ++k) s += P[(size_t)k * 16384 + e];
    Psum[e] = s;
  }
}

// ---------------------------------------------------------------------------
// K3: blocked Gauss-Jordan inverse (nb=16), register-resident 8x8 tiles.
// alpha computed inline from cnt. grid 129, block 256.
#define SWZ(c) (((c) & 14) | (((c) & 1) << 4) | (((c) >> 4) & 1))

__global__ __launch_bounds__(256, 1) void k3_invert(
    const float* __restrict__ P, const float* __restrict__ Psum,
    const float* __restrict__ cnt, float* __restrict__ C) {
  __shared__ float Mt[16 * 132];   // M transposed: Mt[q*132 + row], 8.4 KB
  __shared__ float Rb[16 * 128];   // R rows, float4-quad bit0<->bit4 swizzle, 8 KB
  __shared__ float redc[4];
  int blk = blockIdx.x;
  int t = threadIdx.x;
  int tx = t & 15, ty = t >> 4;

  // inline alpha: total = sum(cnt), then per-block alpha
  float cv = cnt[t & 127];
  float sr = cv;
  #pragma unroll
  for (int o = 32; o > 0; o >>= 1) sr += __shfl_down(sr, o, 64);
  if ((t & 63) == 0) redc[t >> 6] = sr;
  __syncthreads();
  float total = redc[0] + redc[1];  // waves 0,1 cover cnt[0..127]
  bool has = total > 1e-6f;
  float av;
  if (blk < 128) {
    float c = cnt[blk];
    float bk = (c != 0.0f) ? 1.0f : 0.0f;
    float cfix = c + (1.0f - bk);
    av = (float)Nn / (cfix * EPS2) * bk;
  } else {
    av = has ? ((float)Nn / (EPS2 * total)) : 0.0f;
  }
  const float* src = (blk < 128) ? (P + (size_t)blk * 16384) : Psum;

  // init a = av*src + I
  float a[8][8];
  #pragma unroll
  for (int i = 0; i < 8; ++i) {
    int row = ty * 8 + i;
    float4 p0 = *(const float4*)&src[row * 128 + tx * 8];
    float4 p1 = *(const float4*)&src[row * 128 + tx * 8 + 4];
    a[i][0] = av * p0.x; a[i][1] = av * p0.y; a[i][2] = av * p0.z; a[i][3] = av * p0.w;
    a[i][4] = av * p1.x; a[i][5] = av * p1.y; a[i][6] = av * p1.z; a[i][7] = av * p1.w;
    if (tx == ty) a[i][i] += 1.0f;
  }

  for (int kb = 0; kb < 8; ++kb) {
    int k0 = kb * 16;
    // --- Phase A: dumps ---
    if ((ty >> 1) == kb) {          // R: pre-panel pivot rows (full 128 cols)
      int d = ty & 1;
      #pragma unroll
      for (int i = 0; i < 8; ++i) {
        *(float4*)&Rb[(d * 8 + i) * 128 + SWZ(2 * tx) * 4] =
            make_float4(a[i][0], a[i][1], a[i][2], a[i][3]);
        *(float4*)&Rb[(d * 8 + i) * 128 + SWZ(2 * tx + 1) * 4] =
            make_float4(a[i][4], a[i][5], a[i][6], a[i][7]);
      }
    }
    if ((tx >> 1) == kb) {          // M pre-panel values, transposed
      int dh = tx & 1;
      #pragma unroll
      for (int i = 0; i < 8; ++i)
        #pragma unroll
        for (int j = 0; j < 8; ++j)
          Mt[(dh * 8 + j) * 132 + ty * 8 + i] = a[i][j];
    }
    __syncthreads();

    // --- Phase B: wave 0 factors the 128x16 panel (no barriers inside) ---
    if (t < 64) {
      int l = t;
      float m[2][16];
      #pragma unroll
      for (int d = 0; d < 2; ++d)
        #pragma unroll
        for (int j = 0; j < 16; ++j)
          m[d][j] = Mt[j * 132 + 2 * l + d];
      #pragma unroll
      for (int q = 0; q < 16; ++q) {
        int lq = (k0 + q) >> 1;           // uniform source lane
        float pr[16];
        #pragma unroll
        for (int j = 0; j < 16; ++j) pr[j] = __shfl(m[q & 1][j], lq, 64);
        float pinv = 1.0f / pr[q];
        #pragma unroll
        for (int d = 0; d < 2; ++d) {
          float f = m[d][q];
          bool isp = (2 * l + d == k0 + q);
          float g = isp ? (1.0f - pinv) : f * pinv;
          #pragma unroll
          for (int j = 0; j < 16; ++j) m[d][j] = fmaf(-g, pr[j], m[d][j]);
          m[d][q] = isp ? pinv : -g;
        }
      }
      #pragma unroll
      for (int d = 0; d < 2; ++d)
        #pragma unroll
        for (int j = 0; j < 16; ++j)
          Mt[j * 132 + 2 * l + d] = m[d][j];
    }
    __syncthreads();

    // --- Phase C: rank-16 trailing update ---
    if ((ty >> 1) == kb) {          // panel rows: old value dropped
      #pragma unroll
      for (int i = 0; i < 8; ++i)
        #pragma unroll
        for (int j = 0; j < 8; ++j) a[i][j] = 0.0f;
    }
    #pragma unroll
    for (int q = 0; q < 16; ++q) {
      float4 m0 = *(const float4*)&Mt[q * 132 + ty * 8];
      float4 m1 = *(const float4*)&Mt[q * 132 + ty * 8 + 4];
      float4 r0 = *(const float4*)&Rb[q * 128 + SWZ(2 * tx) * 4];
      float4 r1 = *(const float4*)&Rb[q * 128 + SWZ(2 * tx + 1) * 4];
      float mq[8] = {m0.x, m0.y, m0.z, m0.w, m1.x, m1.y, m1.z, m1.w};
      float rq[8] = {r0.x, r0.y, r0.z, r0.w, r1.x, r1.y, r1.z, r1.w};
      #pragma unroll
      for (int i = 0; i < 8; ++i)
        #pragma unroll
        for (int j = 0; j < 8; ++j)
          a[i][j] = fmaf(mq[i], rq[j], a[i][j]);
    }
    if ((tx >> 1) == kb) {          // panel cols: value IS M (reload)
      int dh = tx & 1;
      #pragma unroll
      for (int j = 0; j < 8; ++j) {
        float4 v0 = *(const float4*)&Mt[(dh * 8 + j) * 132 + ty * 8];
        float4 v1 = *(const float4*)&Mt[(dh * 8 + j) * 132 + ty * 8 + 4];
        a[0][j] = v0.x; a[1][j] = v0.y; a[2][j] = v0.z; a[3][j] = v0.w;
        a[4][j] = v1.x; a[5][j] = v1.y; a[6][j] = v1.z; a[7][j] = v1.w;
      }
    }
    __syncthreads();                // protect Mt/Rb before next panel's dumps
  }

  // scale by alpha and store
  float* dst = C + (size_t)blk * 16384;
  #pragma unroll
  for (int i = 0; i < 8; ++i) {
    int row = ty * 8 + i;
    float4 v0 = make_float4(av * a[i][0], av * a[i][1], av * a[i][2], av * a[i][3]);
    float4 v1 = make_float4(av * a[i][4], av * a[i][5], av * a[i][6], av * a[i][7]);
    *(float4*)&dst[row * 128 + tx * 8] = v0;
    *(float4*)&dst[row * 128 + tx * 8 + 4] = v1;
  }
}

// ---------------------------------------------------------------------------
// K45 v2 (LDS-tiled, fused): blocks 0..127: G_k = c_k^T c_k (full 64 KB c_k in
// LDS, 8x8 outputs/thread). Blocks 128..191: S_b = xn_b xn_b^T, (b = bxx>>1,
// col-half = bxx&1), 33 KB X-tile. One shared 64 KB buffer. grid 192, block 256.
__global__ __launch_bounds__(256, 1) void k45_gram_S(
    const float* __restrict__ C, const float* __restrict__ xn,
    float* __restrict__ G, float* __restrict__ S) {
  __shared__ __align__(16) float LB[128 * 128];  // 64 KB, shared by both paths
  int bx = blockIdx.x;
  int t = threadIdx.x;
  int tx = t & 15, ty = t >> 4;
  if (bx < 128) {
    int k = bx;
    const float* src = C + (size_t)k * 16384;
    for (int c = 0; c < 64; ++c) LB[c * 256 + t] = src[c * 256 + t];
    __syncthreads();
    int i0 = ty * 8, j0 = tx * 8;
    float acc[8][8] = {};
    for (int l = 0; l < 128; ++l) {
      float ai[8], bj[8];
      *(float4*)&ai[0] = *(const float4*)&LB[l * 128 + i0];
      *(float4*)&ai[4] = *(const float4*)&LB[l * 128 + i0 + 4];
      *(float4*)&bj[0] = *(const float4*)&LB[l * 128 + j0];
      *(float4*)&bj[4] = *(const float4*)&LB[l * 128 + j0 + 4];
      #pragma unroll
      for (int qi = 0; qi < 8; ++qi)
        #pragma unroll
        for (int qj = 0; qj < 8; ++qj)
          acc[qi][qj] = fmaf(ai[qi], bj[qj], acc[qi][qj]);
    }
    float* dst = G + (size_t)k * 16384;
    #pragma unroll
    for (int qi = 0; qi < 8; ++qi) {
      float4 v0 = make_float4(acc[qi][0], acc[qi][1], acc[qi][2], acc[qi][3]);
      float4 v1 = make_float4(acc[qi][4], acc[qi][5], acc[qi][6], acc[qi][7]);
      *(float4*)&dst[(i0 + qi) * 128 + j0] = v0;
      *(float4*)&dst[(i0 + qi) * 128 + j0 + 4] = v1;
    }
  } else {
    int bxx = bx - 128;
    int b = bxx >> 1;
    int jbase = (bxx & 1) * 64;
    float* X = LB;  // uses 128*65 floats (33.3 KB), pad 65 breaks conflicts
    float acc[8][4] = {};
    for (int mc = 0; mc < Mm; mc += 64) {
      __syncthreads();
      for (int c = 0; c < 32; ++c) {
        int e = c * 256 + t;
        int i = e >> 6, mm = e & 63;
        X[i * 65 + mm] = xn[(size_t)b * (Nn * Mm) + i * Mm + mc + mm];
      }
      __syncthreads();
      for (int mm = 0; mm < 64; ++mm) {
        float ai[8], bj[4];
        #pragma unroll
        for (int q = 0; q < 8; ++q) ai[q] = X[(ty * 8 + q) * 65 + mm];
        #pragma unroll
        for (int q = 0; q < 4; ++q) bj[q] = X[(jbase + tx * 4 + q) * 65 + mm];
        #pragma unroll
        for (int qi = 0; qi < 8; ++qi)
          #pragma unroll
          for (int qj = 0; qj < 4; ++qj)
            acc[qi][qj] = fmaf(ai[qi], bj[qj], acc[qi][qj]);
      }
    }
    float* dst = S + (size_t)b * 16384;
    #pragma unroll
    for (int qi = 0; qi < 8; ++qi) {
      float4 v = make_float4(acc[qi][0], acc[qi][1], acc[qi][2], acc[qi][3]);
      *(float4*)&dst[(ty * 8 + qi) * 128 + jbase + tx * 4] = v;
    }
  }
}

// ---------------------------------------------------------------------------
// K6: partial[c][b][k] = sum over inner chunk c (64 of 16384) of G[k][.]*S[b][.].
// grid 256, block 256.
__global__ __launch_bounds__(256, 1) void k6_partial(const float* __restrict__ G,
                                                     const float* __restrict__ S,
                                                     float* __restrict__ part) {
  int c = blockIdx.x;
  int t = threadIdx.x;
  __shared__ float Gp[128 * 65];  // 33.3 KB
  __shared__ float Sp[32 * 65];   // 8.3 KB
  int off = c * 64;
  for (int q = 0; q < 32; ++q) {
    int e = q * 256 + t;
    int k = e >> 6, jj = e & 63;
    Gp[k * 65 + jj] = G[(size_t)k * 16384 + off + jj];
  }
  for (int q = 0; q < 8; ++q) {
    int e = q * 256 + t;
    int b = e >> 6, jj = e & 63;
    Sp[b * 65 + jj] = S[(size_t)b * 16384 + off + jj];
  }
  __syncthreads();
  int tk = t & 15, tb = t >> 4;  // k = tk + 16q (bank-friendly), b = tb*2 + bb
  float acc[2][8] = {};
  for (int jj = 0; jj < 64; ++jj) {
    float sv0 = Sp[(tb * 2) * 65 + jj];
    float sv1 = Sp[(tb * 2 + 1) * 65 + jj];
    float gv[8];
    #pragma unroll
    for (int q = 0; q < 8; ++q) gv[q] = Gp[(tk + 16 * q) * 65 + jj];
    #pragma unroll
    for (int q = 0; q < 8; ++q) {
      acc[0][q] = fmaf(sv0, gv[q], acc[0][q]);
      acc[1][q] = fmaf(sv1, gv[q], acc[1][q]);
    }
  }
  float* pout = part + (size_t)c * 4096;
  #pragma unroll
  for (int bb = 0; bb < 2; ++bb)
    #pragma unroll
    for (int q = 0; q < 8; ++q)
      pout[(tb * 2 + bb) * 128 + tk + 16 * q] = acc[bb][q];
}

// ---------------------------------------------------------------------------
// K7: reduce partials -> norm -> rescale to sum 10 -> softmax -> w[k][b]=gama*pi.
// gama/total computed inline from cnt. grid 32 (one per b), block 256.
__global__ void k7_weights(const float* __restrict__ part,
                           const float* __restrict__ cnt, float* __restrict__ wT) {
  int b = blockIdx.x;
  int t = threadIdx.x;
  int k = t & 127, h = t >> 7;
  float s = 0.f;
  #pragma unroll 8
  for (int c = h * 128; c < h * 128 + 128; ++c)
    s += part[(size_t)c * 4096 + b * 128 + k];
  __shared__ float sh[256];
  sh[t] = s;
  __syncthreads();
  float norm2 = sh[k] + sh[k + 128];  // both halves compute identical values
  float norm = sqrtf(fmaxf(norm2, 0.0f));
  float cv = cnt[k];
  // total over k (waves 0,1 cover k=0..127)
  float tt = cv;
  #pragma unroll
  for (int o = 32; o > 0; o >>= 1) tt += __shfl_down(tt, o, 64);
  __shared__ float redt[4];
  if ((t & 63) == 0) redt[t >> 6] = tt;
  // sum of norms over 256 threads = 2 * (sum over k)
  float r = norm;
  #pragma unroll
  for (int o = 32; o > 0; o >>= 1) r += __shfl_down(r, o, 64);
  __shared__ float red[4];
  if ((t & 63) == 0) red[t >> 6] = r;
  __syncthreads();
  float total = redt[0] + redt[1];
  float sumn = 0.5f * (red[0] + red[1] + red[2] + red[3]);
  float nr = 10.0f * norm / fmaxf(sumn, 1e-30f);
  float ex = expf(-LAMBDA_S * nr);
  float r2 = ex;
  #pragma unroll
  for (int o = 32; o > 0; o >>= 1) r2 += __shfl_down(r2, o, 64);
  __shared__ float red2[4];
  if ((t & 63) == 0) red2[t >> 6] = r2;
  __syncthreads();
  float sume = 0.5f * (red2[0] + red2[1] + red2[2] + red2[3]);
  float bk = (cv != 0.0f) ? 1.0f : 0.0f;
  float pi = (ex / sume) * bk;
  float gama = (total > 1e-6f) ? (cv / total) : 0.0f;
  if (h == 0) wT[k * 32 + b] = gama * pi;  // transposed for K8 scalar loads
}

// ---------------------------------------------------------------------------
// K8: F[b] = e - sum_k w[b][k] * c_k. grid (64,4), block 256; each thread
// one (i,j) element x 8 b-accumulators.
__global__ __launch_bounds__(256, 1) void k8_F(const float* __restrict__ C,
                                               const float* __restrict__ E,
                                               const float* __restrict__ wT,
                                               float* __restrict__ F) {
  int e = blockIdx.x * 256 + threadIdx.x;
  int b0 = blockIdx.y * 8;
  float acc[8];
  float ev = E[e];
  #pragma unroll
  for (int b = 0; b < 8; ++b) acc[b] = ev;
  for (int k = 0; k < 128; ++k) {
    float cv = C[(size_t)k * 16384 + e];
    const float* wk = wT + k * 32 + b0;  // uniform -> s_load
    #pragma unroll
    for (int b = 0; b < 8; ++b) acc[b] = fmaf(-wk[b], cv, acc[b]);
  }
  #pragma unroll
  for (int b = 0; b < 8; ++b) F[(size_t)(b0 + b) * 16384 + e] = acc[b];
}

// ---------------------------------------------------------------------------
// K9 (LDS-tiled): out[b] = xn[b] + LR * F[b] @ xn[b]. grid (32,4): m-quarter.
// block 256, 8x4 outputs/thread.
__global__ __launch_bounds__(256, 1) void k9_out(const float* __restrict__ F,
                                                 const float* __restrict__ xn,
                                                 float* __restrict__ out) {
  int b = blockIdx.x;
  int mq = blockIdx.y;
  __shared__ __align__(16) float Ft[128 * 65];  // 33.3 KB
  __shared__ __align__(16) float Xt[64 * 65];   // 16.6 KB
  int t = threadIdx.x;
  int tx = t & 15, ty = t >> 4;
  int i0 = ty * 8, m0 = mq * 64 + tx * 4;
  float acc[8][4] = {};
  for (int jc = 0; jc < 128; jc += 64) {
    __syncthreads();
    for (int q = 0; q < 32; ++q) {
      int e = q * 256 + t;
      int i = e >> 6, jj = e & 63;
      Ft[i * 65 + jj] = F[(size_t)b * 16384 + i * 128 + jc + jj];
    }
    for (int q = 0; q < 16; ++q) {
      int e = q * 256 + t;
      int jj = e >> 6, mm = e & 63;
      Xt[jj * 65 + mm] = xn[(size_t)b * (Nn * Mm) + (jc + jj) * Mm + mq * 64 + mm];
    }
    __syncthreads();
    for (int jj = 0; jj < 64; ++jj) {
      float fi[8], xm[4];
      #pragma unroll
      for (int q = 0; q < 8; ++q) fi[q] = Ft[(i0 + q) * 65 + jj];
      #pragma unroll
      for (int q = 0; q < 4; ++q) xm[q] = Xt[jj * 65 + tx * 4 + q];
      #pragma unroll
      for (int qi = 0; qi < 8; ++qi)
        #pragma unroll
        for (int qj = 0; qj < 4; ++qj)
          acc[qi][qj] = fmaf(fi[qi], xm[qj], acc[qi][qj]);
    }
  }
  #pragma unroll
  for (int qi = 0; qi < 8; ++qi) {
    int i = i0 + qi;
    float4 xv = *(const float4*)&xn[(size_t)b * (Nn * Mm) + i * Mm + m0];
    float4 o;
    o.x = fmaf(LR, acc[qi][0], xv.x);
    o.y = fmaf(LR, acc[qi][1], xv.y);
    o.z = fmaf(LR, acc[qi][2], xv.z);
    o.w = fmaf(LR, acc[qi][3], xv.w);
    *(float4*)&out[(size_t)b * (Nn * Mm) + i * Mm + m0] = o;
  }
}

// ---------------------------------------------------------------------------
extern "C" void kernel_launch(void* const* d_in, const int* in_sizes, int n_in,
                              void* d_out, int out_size, void* d_ws, size_t ws_size,
                              hipStream_t stream) {
  const float* x = (const float*)d_in[0];     // (32,128,256)
  const float* P = (const float*)d_in[1];     // (128,128,128) EC_proto
  const float* cnt = (const float*)d_in[2];   // (128,)
  float* out = (float*)d_out;

  float* ws = (float*)d_ws;
  float* xn = ws;                               // 1048576
  float* C = xn + 1048576;                      // 129*16384 (c_k; slot 128 = e)
  float* G = C + 2113536;                       // 2097152
  float* S = G + 2097152;                       // 524288
  float* part = S + 524288;                     // 1048576
  float* F = part + 1048576;                    // 524288
  float* wT = F + 524288;                       // 4096
  float* Psum = wT + 4096;                      // 16384
  size_t need_bytes = (size_t)((Psum + 16384) - ws) * sizeof(float);
  if (ws_size < need_bytes) return;  // ~29.5 MB required

  hipLaunchKernelGGL(kA_bn_psum, dim3(192), dim3(256), 0, stream, x, P, xn, Psum);
  hipLaunchKernelGGL(k3_invert, dim3(129), dim3(256), 0, stream, P, Psum, cnt, C);
  hipLaunchKernelGGL(k45_gram_S, dim3(192), dim3(256), 0, stream, C, xn, G, S);
  hipLaunchKernelGGL(k6_partial, dim3(256), dim3(256), 0, stream, G, S, part);
  hipLaunchKernelGGL(k7_weights, dim3(32), dim3(256), 0, stream, part, cnt, wT);
  hipLaunchKernelGGL(k8_F, dim3(64, 4), dim3(256), 0, stream, C, C + (size_t)128 * 16384, wT, F);
  hipLaunchKernelGGL(k9_out, dim3(32, 4), dim3(256), 0, stream, F, xn, out);
}